// Round 15
// baseline (947.210 us; speedup 1.0000x reference)
//
#include <hip/hip_runtime.h>
#include <math.h>

#define T_STEPS 512
#define IN_DIM  32
#define H       64
#define NBATCH  32     // batch rows per block (2 groups of 16); grid = 32
#define PK0     100    // padded K for B0 rows (x: k 0-31 | h0: k 32-95)
#define PK1     132    // padded K for B1 rows (h0: k 0-63 | h1: k 64-127)

typedef _Float16 half8 __attribute__((ext_vector_type(8)));
typedef _Float16 half4 __attribute__((ext_vector_type(4)));
typedef float    f32x4 __attribute__((ext_vector_type(4)));

__device__ __forceinline__ float sigmoid_f(float x) {
    float e = __expf(-x);
    return __builtin_amdgcn_rcpf(1.0f + e);
}
__device__ __forceinline__ float tanh_f(float x) {
    float e = __expf(2.0f * x);
    return 1.0f - 2.0f * __builtin_amdgcn_rcpf(1.0f + e);
}

// A-fragment for v_mfma_f32_16x16x32_f16 from row-major f32 W (row stride K):
// lane l holds A[m][kb+{0..3}] elems 0-3, A[m][kb+16+{0..3}] elems 4-7,
// m = l&15, kb = c0 + (l>>4)*4.
__device__ __forceinline__ half8 load_afrag(const float* __restrict__ W, int K,
                                            int m, int kb) {
    const float4 a = *reinterpret_cast<const float4*>(W + (size_t)m * K + kb);
    const float4 b = *reinterpret_cast<const float4*>(W + (size_t)m * K + kb + 16);
    half8 r;
    r[0] = (_Float16)a.x; r[1] = (_Float16)a.y; r[2] = (_Float16)a.z; r[3] = (_Float16)a.w;
    r[4] = (_Float16)b.x; r[5] = (_Float16)b.y; r[6] = (_Float16)b.z; r[7] = (_Float16)b.w;
    return r;
}

// B-fragment: LDS stores operand as [n][k] rows. Lane l reads B[k0+{0..3}][n]
// and B[k0+16+{0..3}][n]; rowbase = &lds[n][0], k0 = ktile*32 + (l>>4)*4.
__device__ __forceinline__ half8 read_bfrag(const _Float16* rowbase, int k0) {
    uint2 lo = *reinterpret_cast<const uint2*>(rowbase + k0);
    uint2 hi = *reinterpret_cast<const uint2*>(rowbase + k0 + 16);
    uint4 u; u.x = lo.x; u.y = lo.y; u.z = hi.x; u.w = hi.y;
    return __builtin_bit_cast(half8, u);
}

// Pipelined 2-layer LSTM on MFMA, TWO independent batch-16 groups per block.
// Waves 0-7: group 0 (batch cols 0-15), waves 8-15: group 1 (cols 16-31).
// Within a group: waves 0-3 = layer 0 (IFGO M-tiles {w,w+4,w+8,w+12}),
// waves 4-7 = layer 1 one step behind. C/D layout (HW-verified):
// col=lane&15 (batch), row=(lane>>4)*4+reg (h-idx). One barrier/iter.
// R15: 4 waves/SIMD so one group's waves fill the other's ds/MFMA stalls.
__launch_bounds__(1024, 1)
__global__ void lstm_forecast_kernel(
    const float* __restrict__ seq, const int* __restrict__ line_id,
    const float* __restrict__ embed,
    const float* __restrict__ w_ih0, const float* __restrict__ w_hh0,
    const float* __restrict__ b_ih0, const float* __restrict__ b_hh0,
    const float* __restrict__ w_ih1, const float* __restrict__ w_hh1,
    const float* __restrict__ b_ih1, const float* __restrict__ b_hh1,
    const float* __restrict__ w1, const float* __restrict__ b1,
    const float* __restrict__ w2, const float* __restrict__ b2,
    float* __restrict__ out)
{
    const int tid  = threadIdx.x;
    const int lane = tid & 63;
    const int wid  = tid >> 6;         // 0-15
    const int sub  = wid >> 3;         // batch subgroup 0/1
    const int wsub = wid & 7;          // wave role within group
    const int lmod = lane & 15;        // A m-idx / B-C-D col within group
    const int lgrp = lane >> 4;
    const int rowbase = lgrp * 4;
    const int kb = lgrp * 4;
    const int b0 = blockIdx.x * NBATCH;
    const int bn = lmod + 16 * sub;    // LDS batch row for B/C/D access

    __shared__ _Float16 B0[2][NBATCH][PK0];
    __shared__ _Float16 B1[2][NBATCH][PK1];
    __shared__ float fc1_lds[NBATCH][H];

    const bool isL0 = (wsub < 4);
    const int  w    = wsub & 3;

    // ---- persistent A-fragments (weights) + per-lane bias ----
    half8 Af[4][4];
    f32x4 bv[4];
    #pragma unroll
    for (int G = 0; G < 4; ++G) {
        const int m = (w + 4 * G) * 16 + lmod;
        const int rw = (w + 4 * G) * 16 + rowbase;
        if (isL0) {
            Af[G][0] = load_afrag(w_ih0, IN_DIM, m, kb);
            Af[G][1] = load_afrag(w_hh0, H, m, kb);
            Af[G][2] = load_afrag(w_hh0, H, m, 32 + kb);
            Af[G][3] = Af[G][2];  // unused
            f32x4 b;
            #pragma unroll
            for (int r = 0; r < 4; ++r) b[r] = b_ih0[rw + r] + b_hh0[rw + r];
            bv[G] = b;
        } else {
            Af[G][0] = load_afrag(w_ih1, H, m, kb);
            Af[G][1] = load_afrag(w_ih1, H, m, 32 + kb);
            Af[G][2] = load_afrag(w_hh1, H, m, kb);
            Af[G][3] = load_afrag(w_hh1, H, m, 32 + kb);
            f32x4 b;
            #pragma unroll
            for (int r = 0; r < 4; ++r) b[r] = b_ih1[rw + r] + b_hh1[rw + r];
            bv[G] = b;
        }
    }

    float cst[4] = {0.f, 0.f, 0.f, 0.f};   // cell state

    // ---- zero init h0 / h1[-1]; stage x[0]; preload x[1] into register ----
    const int sn = tid >> 5, si = tid & 31;    // 32 rows x 32 elems
    const size_t sbase = ((size_t)(b0 + sn) * T_STEPS) * IN_DIM + si;
    {
        const int zk = si * 2;
        *reinterpret_cast<unsigned*>(&B0[0][sn][32 + zk]) = 0u;
        *reinterpret_cast<unsigned*>(&B1[1][sn][64 + zk]) = 0u;
        B0[0][sn][si] = (_Float16)seq[sbase];
    }
    float xv1 = seq[sbase + IN_DIM];   // x[1]
    __syncthreads();

    const int hidx0 = w * 16 + rowbase;
    const f32x4 zf = {0.f, 0.f, 0.f, 0.f};

    #pragma unroll 1
    for (int t = 0; t <= T_STEPS; ++t) {
        const int cur = t & 1, nxt = cur ^ 1;

        // write x[t+1] (already in register) at iteration START;
        // then issue x[t+2] load -- a full iteration to cover HBM latency.
        if (t + 1 < T_STEPS) B0[nxt][sn][si] = (_Float16)xv1;
        float xnew = 0.f;
        if (t + 2 < T_STEPS) xnew = seq[sbase + (size_t)(t + 2) * IN_DIM];

        if (isL0) {
            if (t < T_STEPS) {
                const _Float16* bb = &B0[cur][bn][0];
                const half8 Bx   = read_bfrag(bb, kb);
                const half8 Bh0a = read_bfrag(bb, 32 + kb);
                const half8 Bh0b = read_bfrag(bb, 64 + kb);
                f32x4 A0 = bv[0], A1 = bv[1], A2 = bv[2], A3 = bv[3];
                f32x4 D0 = zf, D1 = zf, D2 = zf, D3 = zf;
                A0 = __builtin_amdgcn_mfma_f32_16x16x32_f16(Af[0][0], Bx,   A0, 0, 0, 0);
                A1 = __builtin_amdgcn_mfma_f32_16x16x32_f16(Af[1][0], Bx,   A1, 0, 0, 0);
                A2 = __builtin_amdgcn_mfma_f32_16x16x32_f16(Af[2][0], Bx,   A2, 0, 0, 0);
                A3 = __builtin_amdgcn_mfma_f32_16x16x32_f16(Af[3][0], Bx,   A3, 0, 0, 0);
                D0 = __builtin_amdgcn_mfma_f32_16x16x32_f16(Af[0][1], Bh0a, D0, 0, 0, 0);
                D1 = __builtin_amdgcn_mfma_f32_16x16x32_f16(Af[1][1], Bh0a, D1, 0, 0, 0);
                D2 = __builtin_amdgcn_mfma_f32_16x16x32_f16(Af[2][1], Bh0a, D2, 0, 0, 0);
                D3 = __builtin_amdgcn_mfma_f32_16x16x32_f16(Af[3][1], Bh0a, D3, 0, 0, 0);
                A0 = __builtin_amdgcn_mfma_f32_16x16x32_f16(Af[0][2], Bh0b, A0, 0, 0, 0);
                A1 = __builtin_amdgcn_mfma_f32_16x16x32_f16(Af[1][2], Bh0b, A1, 0, 0, 0);
                A2 = __builtin_amdgcn_mfma_f32_16x16x32_f16(Af[2][2], Bh0b, A2, 0, 0, 0);
                A3 = __builtin_amdgcn_mfma_f32_16x16x32_f16(Af[3][2], Bh0b, A3, 0, 0, 0);
                const f32x4 C0 = A0 + D0, C1 = A1 + D1, C2 = A2 + D2, C3 = A3 + D3;
                half4 hh;
                #pragma unroll
                for (int r = 0; r < 4; ++r) {
                    float ig = sigmoid_f(C0[r]);
                    float fg = sigmoid_f(C1[r]);
                    float gg = tanh_f(C2[r]);
                    float og = sigmoid_f(C3[r]);
                    cst[r] = fg * cst[r] + ig * gg;
                    hh[r] = (_Float16)(og * tanh_f(cst[r]));
                }
                const uint2 hu = __builtin_bit_cast(uint2, hh);
                *reinterpret_cast<uint2*>(&B0[nxt][bn][32 + hidx0]) = hu;
                *reinterpret_cast<uint2*>(&B1[nxt][bn][hidx0]) = hu;
            }
        } else {
            if (t >= 1) {
                const _Float16* bb = &B1[cur][bn][0];
                const half8 Bh0a = read_bfrag(bb, kb);
                const half8 Bh0b = read_bfrag(bb, 32 + kb);
                const half8 Bh1a = read_bfrag(bb, 64 + kb);
                const half8 Bh1b = read_bfrag(bb, 96 + kb);
                f32x4 A0 = bv[0], A1 = bv[1], A2 = bv[2], A3 = bv[3];
                f32x4 D0 = zf, D1 = zf, D2 = zf, D3 = zf;
                A0 = __builtin_amdgcn_mfma_f32_16x16x32_f16(Af[0][0], Bh0a, A0, 0, 0, 0);
                A1 = __builtin_amdgcn_mfma_f32_16x16x32_f16(Af[1][0], Bh0a, A1, 0, 0, 0);
                A2 = __builtin_amdgcn_mfma_f32_16x16x32_f16(Af[2][0], Bh0a, A2, 0, 0, 0);
                A3 = __builtin_amdgcn_mfma_f32_16x16x32_f16(Af[3][0], Bh0a, A3, 0, 0, 0);
                D0 = __builtin_amdgcn_mfma_f32_16x16x32_f16(Af[0][2], Bh1a, D0, 0, 0, 0);
                D1 = __builtin_amdgcn_mfma_f32_16x16x32_f16(Af[1][2], Bh1a, D1, 0, 0, 0);
                D2 = __builtin_amdgcn_mfma_f32_16x16x32_f16(Af[2][2], Bh1a, D2, 0, 0, 0);
                D3 = __builtin_amdgcn_mfma_f32_16x16x32_f16(Af[3][2], Bh1a, D3, 0, 0, 0);
                A0 = __builtin_amdgcn_mfma_f32_16x16x32_f16(Af[0][1], Bh0b, A0, 0, 0, 0);
                A1 = __builtin_amdgcn_mfma_f32_16x16x32_f16(Af[1][1], Bh0b, A1, 0, 0, 0);
                A2 = __builtin_amdgcn_mfma_f32_16x16x32_f16(Af[2][1], Bh0b, A2, 0, 0, 0);
                A3 = __builtin_amdgcn_mfma_f32_16x16x32_f16(Af[3][1], Bh0b, A3, 0, 0, 0);
                D0 = __builtin_amdgcn_mfma_f32_16x16x32_f16(Af[0][3], Bh1b, D0, 0, 0, 0);
                D1 = __builtin_amdgcn_mfma_f32_16x16x32_f16(Af[1][3], Bh1b, D1, 0, 0, 0);
                D2 = __builtin_amdgcn_mfma_f32_16x16x32_f16(Af[2][3], Bh1b, D2, 0, 0, 0);
                D3 = __builtin_amdgcn_mfma_f32_16x16x32_f16(Af[3][3], Bh1b, D3, 0, 0, 0);
                const f32x4 C0 = A0 + D0, C1 = A1 + D1, C2 = A2 + D2, C3 = A3 + D3;
                half4 hh;
                #pragma unroll
                for (int r = 0; r < 4; ++r) {
                    float ig = sigmoid_f(C0[r]);
                    float fg = sigmoid_f(C1[r]);
                    float gg = tanh_f(C2[r]);
                    float og = sigmoid_f(C3[r]);
                    cst[r] = fg * cst[r] + ig * gg;
                    hh[r] = (_Float16)(og * tanh_f(cst[r]));
                }
                const uint2 hu = __builtin_bit_cast(uint2, hh);
                *reinterpret_cast<uint2*>(&B1[nxt][bn][64 + hidx0]) = hu;
            }
        }

        xv1 = xnew;
        __syncthreads();
    }

    // ---- head. h1_last lives in B1[1], k 64-127 ----
    {
        const int un = tid & 31;          // batch row 0-31
        const int uk0 = tid >> 5;         // 0-31; handles uk0 and uk0+32
        const int lid = line_id[b0 + un];
        #pragma unroll
        for (int hh = 0; hh < 2; ++hh) {
            const int u = uk0 + 32 * hh;
            float a = b1[u];
            #pragma unroll
            for (int j = 0; j < H; ++j)
                a = fmaf(w1[u * (H + 8) + j], (float)B1[1][un][64 + j], a);
            #pragma unroll
            for (int e = 0; e < 8; ++e)
                a = fmaf(w1[u * (H + 8) + H + e], embed[lid * 8 + e], a);
            fc1_lds[un][u] = fmaxf(a, 0.f);
        }
    }
    __syncthreads();
    if (tid < NBATCH * 5) {
        const int n2 = tid / 5, q = tid - 5 * n2;
        float o = b2[q];
        #pragma unroll
        for (int j = 0; j < H; ++j)
            o = fmaf(w2[q * H + j], fc1_lds[n2][j], o);
        out[(b0 + n2) * 5 + q] = o;
    }
}

extern "C" void kernel_launch(void* const* d_in, const int* in_sizes, int n_in,
                              void* d_out, int out_size, void* d_ws, size_t ws_size,
                              hipStream_t stream) {
    const float* seq     = (const float*)d_in[0];
    const int*   line_id = (const int*)  d_in[1];
    const float* embed   = (const float*)d_in[2];
    const float* w_ih0   = (const float*)d_in[3];
    const float* w_hh0   = (const float*)d_in[4];
    const float* b_ih0   = (const float*)d_in[5];
    const float* b_hh0   = (const float*)d_in[6];
    const float* w_ih1   = (const float*)d_in[7];
    const float* w_hh1   = (const float*)d_in[8];
    const float* b_ih1   = (const float*)d_in[9];
    const float* b_hh1   = (const float*)d_in[10];
    const float* w1      = (const float*)d_in[11];
    const float* b1      = (const float*)d_in[12];
    const float* w2      = (const float*)d_in[13];
    const float* b2      = (const float*)d_in[14];
    float* out = (float*)d_out;

    lstm_forecast_kernel<<<dim3(1024 / NBATCH), dim3(1024), 0, stream>>>(
        seq, line_id, embed,
        w_ih0, w_hh0, b_ih0, b_hh0,
        w_ih1, w_hh1, b_ih1, b_hh1,
        w1, b1, w2, b2, out);
}